// Round 3
// baseline (524.092 us; speedup 1.0000x reference)
//
#include <hip/hip_runtime.h>

#define NUM_C 19
#define HW_SHIFT 19                 // H*W = 512*1024 = 2^19
#define HW (1 << HW_SHIFT)          // 524288
#define NPIX (8 * HW)               // B*H*W = 4194304
#define NGROUPS (NPIX / 4)          // float4 groups = 1048576
#define BLOCK 256
#define GRID 2048
#define NTH (GRID * BLOCK)          // 524288 -> exactly 2 grid-stride iterations
#define SLOTS 40                    // 19 nll-sums + 19 counts + 2 pad (160 B, float4-aligned)

// PROBE ROUND: ifl_main is launched TWICE (idempotent pure stores) so that
// dur(this) - dur(next round's single-launch twin) = main's true in-harness cost.
//
// Main: online no-max LSE (logits are N(0,1), exp() safe unshifted; verified
// absmax=0 in r1/r2) + per-thread register histogram (no LDS/global atomics;
// r0-vs-r2 showed per-pixel ds_atomics cost ~15 us) + lane-contiguous float4
// groups (1 KB/wave per load instruction) + per-block partial stores (no
// dependence on the 0xAA-poisoned workspace).
__global__ __launch_bounds__(BLOCK) void ifl_main(const float* __restrict__ x,
                                                  const int* __restrict__ tgt,
                                                  float* __restrict__ part) {
    float acc[NUM_C], cnt[NUM_C];
#pragma unroll
    for (int c = 0; c < NUM_C; ++c) { acc[c] = 0.0f; cnt[c] = 0.0f; }

    const int tid = blockIdx.x * BLOCK + threadIdx.x;

#pragma unroll
    for (int it = 0; it < NGROUPS / NTH; ++it) {
        const int g = tid + it * NTH;           // lane-contiguous float4 groups
        const int p = g << 2;                   // pixel index (4-aligned, never crosses batch)
        const int b = p >> HW_SHIFT;
        const int r = p & (HW - 1);
        const float* base = x + (((size_t)b * NUM_C) << HW_SHIFT) + r;

        const int4 t4 = *reinterpret_cast<const int4*>(tgt + p);

        float s0 = 0.f, s1 = 0.f, s2 = 0.f, s3 = 0.f;
        float x0 = 0.f, x1 = 0.f, x2 = 0.f, x3 = 0.f;
#pragma unroll
        for (int c = 0; c < NUM_C; ++c) {
            const float4 v = *reinterpret_cast<const float4*>(base + ((size_t)c << HW_SHIFT));
            s0 += __expf(v.x); s1 += __expf(v.y); s2 += __expf(v.z); s3 += __expf(v.w);
            x0 = (t4.x == c) ? v.x : x0;
            x1 = (t4.y == c) ? v.y : x1;
            x2 = (t4.z == c) ? v.z : x2;
            x3 = (t4.w == c) ? v.w : x3;
        }
        const float n0 = __logf(s0) - x0;
        const float n1 = __logf(s1) - x1;
        const float n2 = __logf(s2) - x2;
        const float n3 = __logf(s3) - x3;
#pragma unroll
        for (int c = 0; c < NUM_C; ++c) {
            acc[c] += ((t4.x == c) ? n0 : 0.f) + ((t4.y == c) ? n1 : 0.f)
                    + ((t4.z == c) ? n2 : 0.f) + ((t4.w == c) ? n3 : 0.f);
            cnt[c] += ((t4.x == c) ? 1.f : 0.f) + ((t4.y == c) ? 1.f : 0.f)
                    + ((t4.z == c) ? 1.f : 0.f) + ((t4.w == c) ? 1.f : 0.f);
        }
    }

    // wave(64) shuffle reduction -> LDS -> one partial store per block
    __shared__ float red[SLOTS];
    if (threadIdx.x < SLOTS) red[threadIdx.x] = 0.0f;
    __syncthreads();

#pragma unroll
    for (int c = 0; c < NUM_C; ++c) {
        float a = acc[c];
        float n = cnt[c];
#pragma unroll
        for (int off = 32; off > 0; off >>= 1) {
            a += __shfl_down(a, off, 64);
            n += __shfl_down(n, off, 64);
        }
        if ((threadIdx.x & 63) == 0) {
            atomicAdd(&red[c], a);            // 4 colliding lanes max (4 waves/block)
            atomicAdd(&red[NUM_C + c], n);
        }
    }
    __syncthreads();
    if (threadIdx.x < SLOTS) part[blockIdx.x * SLOTS + threadIdx.x] = red[threadIdx.x];
}

// Single block: reduce 2048x40 partials (~320 KB) and emit the weighted mean.
__global__ __launch_bounds__(BLOCK) void ifl_final(const float* __restrict__ part,
                                                   float* __restrict__ out) {
    __shared__ float red[SLOTS];
    if (threadIdx.x < SLOTS) red[threadIdx.x] = 0.0f;
    __syncthreads();

    float acc[SLOTS];
#pragma unroll
    for (int s = 0; s < SLOTS; ++s) acc[s] = 0.0f;

    for (int k = threadIdx.x; k < GRID; k += BLOCK) {
        const float4* p4 = reinterpret_cast<const float4*>(part + (size_t)k * SLOTS);
#pragma unroll
        for (int q = 0; q < SLOTS / 4; ++q) {
            const float4 v = p4[q];
            acc[4 * q + 0] += v.x;
            acc[4 * q + 1] += v.y;
            acc[4 * q + 2] += v.z;
            acc[4 * q + 3] += v.w;
        }
    }

#pragma unroll
    for (int s = 0; s < SLOTS; ++s) {
        float v = acc[s];
#pragma unroll
        for (int off = 32; off > 0; off >>= 1) v += __shfl_down(v, off, 64);
        if ((threadIdx.x & 63) == 0) atomicAdd(&red[s], v);
    }
    __syncthreads();

    if (threadIdx.x == 0) {
        float num = 0.f, den = 0.f;
#pragma unroll
        for (int c = 0; c < NUM_C; ++c) {
            const float cn = red[NUM_C + c];
            const float inv = (cn > 0.f) ? (1.f / fmaxf(cn, 1.f)) : 1.f;
            num += inv * red[c];
            den += inv * cn;
        }
        out[0] = num / den;
    }
}

extern "C" void kernel_launch(void* const* d_in, const int* in_sizes, int n_in,
                              void* d_out, int out_size, void* d_ws, size_t ws_size,
                              hipStream_t stream) {
    const float* x = (const float*)d_in[0];
    const int* tgt = (const int*)d_in[1];
    float* ws = (float*)d_ws;
    float* out = (float*)d_out;

    // PROBE: double-launch. Second launch rewrites identical partials (pure
    // stores, same inputs) -> result unchanged; dur delta vs next round = cost(main).
    ifl_main<<<GRID, BLOCK, 0, stream>>>(x, tgt, ws);
    ifl_main<<<GRID, BLOCK, 0, stream>>>(x, tgt, ws);
    ifl_final<<<1, BLOCK, 0, stream>>>(ws, out);
}

// Round 4
// 451.790 us; speedup vs baseline: 1.1600x; 1.1600x over previous
//
#include <hip/hip_runtime.h>

#define NUM_C 19
#define HW_SHIFT 19                 // H*W = 512*1024 = 2^19
#define HW (1 << HW_SHIFT)          // 524288
#define NPIX (8 * HW)               // B*H*W = 4194304
#define NGROUPS (NPIX / 4)          // float4 groups = 1048576
#define BLOCK 256
#define GRID 2048
#define NTH (GRID * BLOCK)          // 524288 -> exactly 2 unrolled iterations
#define SLOTS 40                    // 19 nll-sums + 19 counts + 2 pad (160 B, float4-aligned)

// Probe-resolved model (r0/r2/r3 system): fixed per-iter overhead F ~= 380 us
// (ws-poison fill 193 + harness restore ~187), r0-style main ~= 55 us vs a
// 52 us BW floor (336 MB @ 6.5 TB/s), my online-LSE rewrites ~= 71 us.
// => Ship r0's measured-best inner loop (batch 19-load -> deep MLP; the exp
// chain interleaving in the online form was the regression), drop its two
// strict overheads: the memset dispatch and global atomics (partial stores
// instead, verified absmax=0 in r2/r3), compile-time trip count.
__global__ __launch_bounds__(BLOCK) void ifl_main(const float* __restrict__ x,
                                                  const int* __restrict__ tgt,
                                                  float* __restrict__ part) {
    float acc[NUM_C], cnt[NUM_C];
#pragma unroll
    for (int c = 0; c < NUM_C; ++c) { acc[c] = 0.0f; cnt[c] = 0.0f; }

    const int tid = blockIdx.x * BLOCK + threadIdx.x;

    union F4 { float4 q; float f[4]; };
    union I4 { int4 q; int i[4]; };

#pragma unroll
    for (int it = 0; it < NGROUPS / NTH; ++it) {
        const int g = tid + it * NTH;           // lane-contiguous float4 groups
        const int p = g << 2;                   // pixel index (4-aligned, never crosses batch)
        const int b = p >> HW_SHIFT;
        const int r = p & (HW - 1);
        const float4* base4 =
            reinterpret_cast<const float4*>(x + (((size_t)b * NUM_C) << HW_SHIFT) + r);

        // batch all 19 plane loads first: 19 outstanding dwordx4/lane (deep MLP)
        F4 v[NUM_C];
#pragma unroll
        for (int c = 0; c < NUM_C; ++c) v[c].q = base4[(size_t)c << (HW_SHIFT - 2)];

        I4 tt;
        tt.q = *reinterpret_cast<const int4*>(tgt + p);

#pragma unroll
        for (int k = 0; k < 4; ++k) {
            const int tg = tt.i[k];
            float m = v[0].f[k];
#pragma unroll
            for (int c = 1; c < NUM_C; ++c) m = fmaxf(m, v[c].f[k]);
            float s = 0.0f;
#pragma unroll
            for (int c = 0; c < NUM_C; ++c) s += __expf(v[c].f[k] - m);
            float xt = v[0].f[k];
#pragma unroll
            for (int c = 1; c < NUM_C; ++c) xt = (tg == c) ? v[c].f[k] : xt;
            const float nll = m + __logf(s) - xt;
#pragma unroll
            for (int c = 0; c < NUM_C; ++c) {
                const bool h = (tg == c);
                acc[c] += h ? nll : 0.0f;
                cnt[c] += h ? 1.0f : 0.0f;
            }
        }
    }

    // wave(64) shuffle reduction -> LDS -> one partial store per block
    __shared__ float red[SLOTS];
    if (threadIdx.x < SLOTS) red[threadIdx.x] = 0.0f;
    __syncthreads();

#pragma unroll
    for (int c = 0; c < NUM_C; ++c) {
        float a = acc[c];
        float n = cnt[c];
#pragma unroll
        for (int off = 32; off > 0; off >>= 1) {
            a += __shfl_down(a, off, 64);
            n += __shfl_down(n, off, 64);
        }
        if ((threadIdx.x & 63) == 0) {
            atomicAdd(&red[c], a);            // <=4 colliding lanes (4 waves/block)
            atomicAdd(&red[NUM_C + c], n);
        }
    }
    __syncthreads();
    if (threadIdx.x < SLOTS) part[blockIdx.x * SLOTS + threadIdx.x] = red[threadIdx.x];
}

// Single block: reduce 2048x40 partials (~320 KB) and emit the weighted mean.
__global__ __launch_bounds__(BLOCK) void ifl_final(const float* __restrict__ part,
                                                   float* __restrict__ out) {
    __shared__ float red[SLOTS];
    if (threadIdx.x < SLOTS) red[threadIdx.x] = 0.0f;
    __syncthreads();

    float acc[SLOTS];
#pragma unroll
    for (int s = 0; s < SLOTS; ++s) acc[s] = 0.0f;

    for (int k = threadIdx.x; k < GRID; k += BLOCK) {
        const float4* p4 = reinterpret_cast<const float4*>(part + (size_t)k * SLOTS);
#pragma unroll
        for (int q = 0; q < SLOTS / 4; ++q) {
            const float4 v = p4[q];
            acc[4 * q + 0] += v.x;
            acc[4 * q + 1] += v.y;
            acc[4 * q + 2] += v.z;
            acc[4 * q + 3] += v.w;
        }
    }

#pragma unroll
    for (int s = 0; s < SLOTS; ++s) {
        float v = acc[s];
#pragma unroll
        for (int off = 32; off > 0; off >>= 1) v += __shfl_down(v, off, 64);
        if ((threadIdx.x & 63) == 0) atomicAdd(&red[s], v);
    }
    __syncthreads();

    if (threadIdx.x == 0) {
        float num = 0.f, den = 0.f;
#pragma unroll
        for (int c = 0; c < NUM_C; ++c) {
            const float cn = red[NUM_C + c];
            const float inv = (cn > 0.f) ? (1.f / fmaxf(cn, 1.f)) : 1.f;
            num += inv * red[c];
            den += inv * cn;
        }
        out[0] = num / den;
    }
}

extern "C" void kernel_launch(void* const* d_in, const int* in_sizes, int n_in,
                              void* d_out, int out_size, void* d_ws, size_t ws_size,
                              hipStream_t stream) {
    const float* x = (const float*)d_in[0];
    const int* tgt = (const int*)d_in[1];
    float* ws = (float*)d_ws;
    float* out = (float*)d_out;

    ifl_main<<<GRID, BLOCK, 0, stream>>>(x, tgt, ws);
    ifl_final<<<1, BLOCK, 0, stream>>>(ws, out);
}